// Round 1
// baseline (968.040 us; speedup 1.0000x reference)
//
#include <hip/hip_runtime.h>
#include <math.h>

#define B_ 2
#define C_ 32
#define D_ 64
#define H_ 128
#define W_ 128
#define N_ (D_*H_*W_)          // 1048576 = 2^20
#define P_CAP 2048
#define NEG_CAP 12288
#define PAD 5
#define TAU_INV 10.0f
#define EPS_ 1e-8f

// ---------------- init: zero counters / accumulators ----------------
__global__ void k_init(int* cnt_pos, int* cnt_neg, float* loss_sum, float* acnt) {
    int t = threadIdx.x;
    if (t < B_) { cnt_pos[t] = 0; cnt_neg[t] = 0; loss_sum[t] = 0.f; acnt[t] = 0.f; }
}

// ---------------- fg mask ----------------
__global__ void k_fg(const int* __restrict__ labels, unsigned char* __restrict__ fg) {
    int g = blockIdx.x * blockDim.x + threadIdx.x;
    if (g >= B_ * N_) return;
    fg[g] = labels[g] > 0 ? 1 : 0;
}

// ---------------- separable binary dilation along one axis ----------------
// coord = (n >> shift) & (size-1); neighbor stride = 1<<shift; window +-PAD clamped
__global__ void k_dil(const unsigned char* __restrict__ in, unsigned char* __restrict__ out,
                      int shift, int size) {
    int g = blockIdx.x * blockDim.x + threadIdx.x;
    if (g >= B_ * N_) return;
    int n = g & (N_ - 1);
    int c = (n >> shift) & (size - 1);
    int stride = 1 << shift;
    int lo = (c >= PAD) ? -PAD : -c;
    int hi = (c + PAD <= size - 1) ? PAD : (size - 1 - c);
    unsigned char v = 0;
    for (int o = lo; o <= hi; ++o) v |= in[g + o * stride];
    out[g] = v;
}

// ---------------- fused D-axis dilation + rim + compaction ----------------
__global__ void k_compact(const unsigned char* __restrict__ t2, const unsigned char* __restrict__ fg,
                          int* __restrict__ pos_idx, int* __restrict__ neg_idx,
                          int* cnt_pos, int* cnt_neg) {
    int g = blockIdx.x * blockDim.x + threadIdx.x;
    if (g >= B_ * N_) return;
    int b = g >> 20;
    int n = g & (N_ - 1);
    unsigned char f = fg[g];
    if (f) {
        int p = atomicAdd(&cnt_pos[b], 1);
        if (p < P_CAP) pos_idx[b * P_CAP + p] = n;
    } else {
        // D-axis dilation on the fly
        int d = n >> 14;
        int lo = (d >= PAD) ? -PAD : -d;
        int hi = (d + PAD <= D_ - 1) ? PAD : (D_ - 1 - d);
        unsigned char v = 0;
        for (int o = lo; o <= hi; ++o) v |= t2[g + o * (H_ * W_)];
        if (v) {
            int p = atomicAdd(&cnt_neg[b], 1);
            if (p < NEG_CAP) neg_idx[b * NEG_CAP + p] = n;
        }
    }
}

// ---------------- gather + L2 normalize selected rows ----------------
__global__ void k_gather(const float* __restrict__ features,
                         const int* __restrict__ pos_idx, const int* __restrict__ neg_idx,
                         const int* __restrict__ cnt_pos, const int* __restrict__ cnt_neg,
                         float* __restrict__ pos_feat, float* __restrict__ neg_feat) {
    const int total = P_CAP + NEG_CAP;
    int g = blockIdx.x * blockDim.x + threadIdx.x;
    if (g >= B_ * total) return;
    int b = g / total, s = g % total;
    int np = min(cnt_pos[b], P_CAP);
    int nn = min(cnt_neg[b], NEG_CAP);
    int idx;
    float* dst;
    if (s < P_CAP) {
        if (s >= np) return;
        idx = pos_idx[b * P_CAP + s];
        dst = pos_feat + ((size_t)b * P_CAP + s) * C_;
    } else {
        int k = s - P_CAP;
        if (k >= nn) return;
        idx = neg_idx[b * NEG_CAP + k];
        dst = neg_feat + ((size_t)b * NEG_CAP + k) * C_;
    }
    const float* fbase = features + (size_t)b * C_ * N_ + idx;
    float v[C_];
    float ss = 0.f;
#pragma unroll
    for (int c = 0; c < C_; ++c) {
        float x = fbase[(size_t)c * N_];
        v[c] = x;
        ss += x * x;
    }
    float inv = 1.0f / fmaxf(sqrtf(ss), 1e-12f);
#pragma unroll
    for (int c = 0; c < C_; ++c) dst[c] = v[c] * inv;
}

// ---------------- per-anchor online-softmax loss ----------------
// merge two (m, sum_pos, sum_neg) triples (sums are of exp(s - m))
__device__ inline void merge3(float& m, float& sn, float& sd, float m2, float sn2, float sd2) {
    if (m2 == -INFINITY) return;
    if (m >= m2) {
        float c = expf(m2 - m);
        sn += sn2 * c;
        sd += sd2 * c;
    } else {
        float c = (m == -INFINITY) ? 0.f : expf(m - m2);
        sn = sn * c + sn2;
        sd = sd * c + sd2;
        m = m2;
    }
}

__global__ __launch_bounds__(256) void k_loss(const float* __restrict__ pos_feat,
                                              const float* __restrict__ neg_feat,
                                              const int* __restrict__ cnt_pos,
                                              const int* __restrict__ cnt_neg,
                                              float* __restrict__ loss_sum,
                                              float* __restrict__ acnt) {
    int b = blockIdx.x / P_CAP;
    int i = blockIdx.x % P_CAP;
    int np = min(cnt_pos[b], P_CAP);
    if (i >= np) return;
    int nn = min(cnt_neg[b], NEG_CAP);
    int tid = threadIdx.x;

    // anchor row -> registers (same address across lanes: HW broadcast)
    const float4* a4 = (const float4*)(pos_feat + ((size_t)b * P_CAP + i) * C_);
    float a[C_];
#pragma unroll
    for (int q = 0; q < 8; ++q) {
        float4 v = a4[q];
        a[4 * q + 0] = v.x; a[4 * q + 1] = v.y; a[4 * q + 2] = v.z; a[4 * q + 3] = v.w;
    }

    float m = -INFINITY, sn = 0.f, sd = 0.f;

    // positives (skip self)
    for (int j = tid; j < np; j += 256) {
        if (j == i) continue;
        const float4* r4 = (const float4*)(pos_feat + ((size_t)b * P_CAP + j) * C_);
        float dot = 0.f;
#pragma unroll
        for (int q = 0; q < 8; ++q) {
            float4 v = r4[q];
            dot = fmaf(v.x, a[4 * q + 0], dot);
            dot = fmaf(v.y, a[4 * q + 1], dot);
            dot = fmaf(v.z, a[4 * q + 2], dot);
            dot = fmaf(v.w, a[4 * q + 3], dot);
        }
        float s = dot * TAU_INV;
        if (s <= m) {
            sn += expf(s - m);
        } else {
            float c = (m == -INFINITY) ? 0.f : expf(m - s);
            sn = sn * c + 1.f;
            sd = sd * c;
            m = s;
        }
    }
    // negatives
    for (int k = tid; k < nn; k += 256) {
        const float4* r4 = (const float4*)(neg_feat + ((size_t)b * NEG_CAP + k) * C_);
        float dot = 0.f;
#pragma unroll
        for (int q = 0; q < 8; ++q) {
            float4 v = r4[q];
            dot = fmaf(v.x, a[4 * q + 0], dot);
            dot = fmaf(v.y, a[4 * q + 1], dot);
            dot = fmaf(v.z, a[4 * q + 2], dot);
            dot = fmaf(v.w, a[4 * q + 3], dot);
        }
        float s = dot * TAU_INV;
        if (s <= m) {
            sd += expf(s - m);
        } else {
            float c = (m == -INFINITY) ? 0.f : expf(m - s);
            sn = sn * c;
            sd = sd * c + 1.f;
            m = s;
        }
    }

    __shared__ float sm[256], ssn[256], ssd[256];
    sm[tid] = m; ssn[tid] = sn; ssd[tid] = sd;
    __syncthreads();
    for (int off = 128; off > 0; off >>= 1) {
        if (tid < off) {
            float M = sm[tid], SN = ssn[tid], SD = ssd[tid];
            merge3(M, SN, SD, sm[tid + off], ssn[tid + off], ssd[tid + off]);
            sm[tid] = M; ssn[tid] = SN; ssd[tid] = SD;
        }
        __syncthreads();
    }
    if (tid == 0) {
        float num = ssn[0] + EPS_;
        float den = ssn[0] + ssd[0] + EPS_;
        bool valid = num > EPS_;
        if (valid) {
            float loss = logf(den) - logf(num);
            atomicAdd(&loss_sum[b], loss);
            atomicAdd(&acnt[b], 1.0f);
        }
    }
}

// ---------------- finalize ----------------
__global__ void k_final(const int* cnt_pos, const int* cnt_neg,
                        const float* loss_sum, const float* acnt, float* out) {
    float tot = 0.f, nv = 0.f;
    bool any = false;
    for (int b = 0; b < B_; ++b) {
        bool valid = (cnt_pos[b] >= 2) && (cnt_neg[b] > 0) && (acnt[b] > 0.f);
        float il = loss_sum[b] / fmaxf(acnt[b], 1.f);
        if (valid) { tot += il; nv += 1.f; any = true; }
    }
    out[0] = any ? tot / fmaxf(nv, 1.f) : 0.f;
}

extern "C" void kernel_launch(void* const* d_in, const int* in_sizes, int n_in,
                              void* d_out, int out_size, void* d_ws, size_t ws_size,
                              hipStream_t stream) {
    const float* features = (const float*)d_in[0];
    const int* labels = (const int*)d_in[1];
    float* out = (float*)d_out;

    // ---- workspace carve (all 4B-aligned; masks last) ----
    char* p = (char*)d_ws;
    float* pos_feat = (float*)p;                 p += (size_t)B_ * P_CAP * C_ * 4;
    float* neg_feat = (float*)p;                 p += (size_t)B_ * NEG_CAP * C_ * 4;
    int* pos_idx = (int*)p;                      p += (size_t)B_ * P_CAP * 4;
    int* neg_idx = (int*)p;                      p += (size_t)B_ * NEG_CAP * 4;
    int* cnt_pos = (int*)p;                      p += B_ * 4;
    int* cnt_neg = (int*)p;                      p += B_ * 4;
    float* loss_sum = (float*)p;                 p += B_ * 4;
    float* acnt = (float*)p;                     p += B_ * 4;
    unsigned char* fg = (unsigned char*)p;       p += (size_t)B_ * N_;
    unsigned char* t1 = (unsigned char*)p;       p += (size_t)B_ * N_;
    unsigned char* t2 = (unsigned char*)p;       p += (size_t)B_ * N_;

    const int threads = 256;
    const int vox_blocks = (B_ * N_ + threads - 1) / threads;

    k_init<<<1, 64, 0, stream>>>(cnt_pos, cnt_neg, loss_sum, acnt);
    k_fg<<<vox_blocks, threads, 0, stream>>>(labels, fg);
    k_dil<<<vox_blocks, threads, 0, stream>>>(fg, t1, 0, W_);   // along W
    k_dil<<<vox_blocks, threads, 0, stream>>>(t1, t2, 7, H_);   // along H
    k_compact<<<vox_blocks, threads, 0, stream>>>(t2, fg, pos_idx, neg_idx, cnt_pos, cnt_neg);
    const int gat_blocks = (B_ * (P_CAP + NEG_CAP) + threads - 1) / threads;
    k_gather<<<gat_blocks, threads, 0, stream>>>(features, pos_idx, neg_idx, cnt_pos, cnt_neg,
                                                 pos_feat, neg_feat);
    k_loss<<<B_ * P_CAP, 256, 0, stream>>>(pos_feat, neg_feat, cnt_pos, cnt_neg, loss_sum, acnt);
    k_final<<<1, 1, 0, stream>>>(cnt_pos, cnt_neg, loss_sum, acnt, out);
}

// Round 2
// 630.942 us; speedup vs baseline: 1.5343x; 1.5343x over previous
//
#include <hip/hip_runtime.h>
#include <math.h>

#define B_ 2
#define C_ 32
#define D_ 64
#define H_ 128
#define W_ 128
#define N_ (D_*H_*W_)          // 1048576 = 2^20
#define P_CAP 2048
#define NEG_CAP 12288
#define PAD 5
#define EPS_ 1e-8f
#define SLICES 32
#define TA 4                   // anchors per thread

// ---------------- init: zero counters / accumulators ----------------
__global__ void k_init(int* cnt_pos, int* cnt_neg, float* loss_sum, float* acnt) {
    int t = threadIdx.x;
    if (t < B_) { cnt_pos[t] = 0; cnt_neg[t] = 0; loss_sum[t] = 0.f; acnt[t] = 0.f; }
}

// ---------------- fg mask ----------------
__global__ void k_fg(const int* __restrict__ labels, unsigned char* __restrict__ fg) {
    int g = blockIdx.x * blockDim.x + threadIdx.x;
    if (g >= B_ * N_) return;
    fg[g] = labels[g] > 0 ? 1 : 0;
}

// ---------------- separable binary dilation along one axis ----------------
__global__ void k_dil(const unsigned char* __restrict__ in, unsigned char* __restrict__ out,
                      int shift, int size) {
    int g = blockIdx.x * blockDim.x + threadIdx.x;
    if (g >= B_ * N_) return;
    int n = g & (N_ - 1);
    int c = (n >> shift) & (size - 1);
    int stride = 1 << shift;
    int lo = (c >= PAD) ? -PAD : -c;
    int hi = (c + PAD <= size - 1) ? PAD : (size - 1 - c);
    unsigned char v = 0;
    for (int o = lo; o <= hi; ++o) v |= in[g + o * stride];
    out[g] = v;
}

// ---------------- fused D-axis dilation + rim + compaction ----------------
__global__ void k_compact(const unsigned char* __restrict__ t2, const unsigned char* __restrict__ fg,
                          int* __restrict__ pos_idx, int* __restrict__ neg_idx,
                          int* cnt_pos, int* cnt_neg) {
    int g = blockIdx.x * blockDim.x + threadIdx.x;
    if (g >= B_ * N_) return;
    int b = g >> 20;
    int n = g & (N_ - 1);
    unsigned char f = fg[g];
    if (f) {
        int p = atomicAdd(&cnt_pos[b], 1);
        if (p < P_CAP) pos_idx[b * P_CAP + p] = n;
    } else {
        int d = n >> 14;
        int lo = (d >= PAD) ? -PAD : -d;
        int hi = (d + PAD <= D_ - 1) ? PAD : (D_ - 1 - d);
        unsigned char v = 0;
        for (int o = lo; o <= hi; ++o) v |= t2[g + o * (H_ * W_)];
        if (v) {
            int p = atomicAdd(&cnt_neg[b], 1);
            if (p < NEG_CAP) neg_idx[b * NEG_CAP + p] = n;
        }
    }
}

// ---------------- gather + L2 normalize selected rows ----------------
__global__ void k_gather(const float* __restrict__ features,
                         const int* __restrict__ pos_idx, const int* __restrict__ neg_idx,
                         const int* __restrict__ cnt_pos, const int* __restrict__ cnt_neg,
                         float* __restrict__ pos_feat, float* __restrict__ neg_feat) {
    const int total = P_CAP + NEG_CAP;
    int g = blockIdx.x * blockDim.x + threadIdx.x;
    if (g >= B_ * total) return;
    int b = g / total, s = g % total;
    int np = min(cnt_pos[b], P_CAP);
    int nn = min(cnt_neg[b], NEG_CAP);
    int idx;
    float* dst;
    if (s < P_CAP) {
        if (s >= np) return;
        idx = pos_idx[b * P_CAP + s];
        dst = pos_feat + ((size_t)b * P_CAP + s) * C_;
    } else {
        int k = s - P_CAP;
        if (k >= nn) return;
        idx = neg_idx[b * NEG_CAP + k];
        dst = neg_feat + ((size_t)b * NEG_CAP + k) * C_;
    }
    const float* fbase = features + (size_t)b * C_ * N_ + idx;
    float v[C_];
    float ss = 0.f;
#pragma unroll
    for (int c = 0; c < C_; ++c) {
        float x = fbase[(size_t)c * N_];
        v[c] = x;
        ss += x * x;
    }
    float inv = 1.0f / fmaxf(sqrtf(ss), 1e-12f);
#pragma unroll
    for (int c = 0; c < C_; ++c) dst[c] = v[c] * inv;
}

// ---------------- partner-sliced loss, fixed softmax shift m=10 ----------------
// Each thread owns TA=4 anchor rows in registers; wave broadcasts partner rows.
// partial layout: [B][SLICES][2][P_CAP]  (comp 0 = pos-sum, comp 1 = neg-sum)
__global__ __launch_bounds__(256) void k_loss2(const float* __restrict__ pos_feat,
                                               const float* __restrict__ neg_feat,
                                               const int* __restrict__ cnt_pos,
                                               const int* __restrict__ cnt_neg,
                                               float* __restrict__ partial) {
    const int slice = blockIdx.x;          // 0..SLICES-1
    const int tile  = blockIdx.y;          // anchor tile (256 anchors each)
    const int b     = blockIdx.z;
    const int np = min(cnt_pos[b], P_CAP);
    const int nn = min(cnt_neg[b], NEG_CAP);
    const int abase = tile * 256;
    if (abase >= np) return;               // block-uniform
    const int total = np + nn;
    const int tid = threadIdx.x;
    const int lane = tid & 63;
    const int w = __builtin_amdgcn_readfirstlane(tid >> 6);   // wave id, SGPR

    // my 4 anchors
    const int a0 = abase + lane * TA;
    float A[TA][C_];
#pragma unroll
    for (int i = 0; i < TA; ++i) {
        const float4* p = (const float4*)(pos_feat + ((size_t)b * P_CAP + (a0 + i)) * C_);
#pragma unroll
        for (int q = 0; q < 8; ++q) {
            float4 v = p[q];
            A[i][4*q+0] = v.x; A[i][4*q+1] = v.y; A[i][4*q+2] = v.z; A[i][4*q+3] = v.w;
        }
    }

    float ps[TA] = {0.f, 0.f, 0.f, 0.f};
    float ns[TA] = {0.f, 0.f, 0.f, 0.f};

    const int per = (total + SLICES - 1) / SLICES;
    const int r0 = slice * per;
    const int r1 = min(r0 + per, total);

#pragma unroll 2
    for (int gr = r0 + w; gr < r1; gr += 4) {
        const float4* row4 = (gr < np)
            ? (const float4*)(pos_feat + ((size_t)b * P_CAP + gr) * C_)
            : (const float4*)(neg_feat + ((size_t)b * NEG_CAP + (gr - np)) * C_);
        float d0 = 0.f, d1 = 0.f, d2 = 0.f, d3 = 0.f;
#pragma unroll
        for (int q = 0; q < 8; ++q) {
            float4 v = row4[q];
            d0 = fmaf(v.x, A[0][4*q+0], d0); d0 = fmaf(v.y, A[0][4*q+1], d0);
            d0 = fmaf(v.z, A[0][4*q+2], d0); d0 = fmaf(v.w, A[0][4*q+3], d0);
            d1 = fmaf(v.x, A[1][4*q+0], d1); d1 = fmaf(v.y, A[1][4*q+1], d1);
            d1 = fmaf(v.z, A[1][4*q+2], d1); d1 = fmaf(v.w, A[1][4*q+3], d1);
            d2 = fmaf(v.x, A[2][4*q+0], d2); d2 = fmaf(v.y, A[2][4*q+1], d2);
            d2 = fmaf(v.z, A[2][4*q+2], d2); d2 = fmaf(v.w, A[2][4*q+3], d2);
            d3 = fmaf(v.x, A[3][4*q+0], d3); d3 = fmaf(v.y, A[3][4*q+1], d3);
            d3 = fmaf(v.z, A[3][4*q+2], d3); d3 = fmaf(v.w, A[3][4*q+3], d3);
        }
        float e0 = __expf(fmaf(d0, 10.f, -10.f));
        float e1 = __expf(fmaf(d1, 10.f, -10.f));
        float e2 = __expf(fmaf(d2, 10.f, -10.f));
        float e3 = __expf(fmaf(d3, 10.f, -10.f));
        if (gr < np) {   // wave-uniform branch
            ps[0] += (gr == a0 + 0) ? 0.f : e0;
            ps[1] += (gr == a0 + 1) ? 0.f : e1;
            ps[2] += (gr == a0 + 2) ? 0.f : e2;
            ps[3] += (gr == a0 + 3) ? 0.f : e3;
        } else {
            ns[0] += e0; ns[1] += e1; ns[2] += e2; ns[3] += e3;
        }
    }

    // reduce the 4 waves' partials (each wave covered a disjoint row subset)
    __shared__ float redP[4][256];
    __shared__ float redN[4][256];
    const int slot = lane * TA;
#pragma unroll
    for (int i = 0; i < TA; ++i) { redP[w][slot + i] = ps[i]; redN[w][slot + i] = ns[i]; }
    __syncthreads();
    {
        float p = redP[0][tid] + redP[1][tid] + redP[2][tid] + redP[3][tid];
        float n = redN[0][tid] + redN[1][tid] + redN[2][tid] + redN[3][tid];
        float* dst = partial + ((size_t)(b * SLICES + slice) * 2) * P_CAP;
        dst[abase + tid] = p;
        dst[P_CAP + abase + tid] = n;
    }
}

// ---------------- per-anchor finalize: sum slices, log, reduce ----------------
__global__ __launch_bounds__(256) void k_loss_fin(const float* __restrict__ partial,
                                                  const int* __restrict__ cnt_pos,
                                                  float* __restrict__ loss_sum,
                                                  float* __restrict__ acnt) {
    const int blocks_per_b = P_CAP / 256;      // 8
    const int b = blockIdx.x / blocks_per_b;
    const int a = (blockIdx.x % blocks_per_b) * 256 + threadIdx.x;
    const int np = min(cnt_pos[b], P_CAP);
    const int tid = threadIdx.x;
    float loss = 0.f, cnt = 0.f;
    if (a < np) {
        float num = 0.f, den = 0.f;
        for (int s = 0; s < SLICES; ++s) {
            const float* base = partial + ((size_t)(b * SLICES + s) * 2) * P_CAP;
            num += base[a];
            den += base[P_CAP + a];
        }
        if (num > 0.f) {
            den += num;
            num += EPS_; den += EPS_;
            loss = __logf(den) - __logf(num);
            cnt = 1.f;
        }
    }
    __shared__ float sl[256], sc[256];
    sl[tid] = loss; sc[tid] = cnt;
    __syncthreads();
    for (int off = 128; off > 0; off >>= 1) {
        if (tid < off) { sl[tid] += sl[tid + off]; sc[tid] += sc[tid + off]; }
        __syncthreads();
    }
    if (tid == 0 && sc[0] > 0.f) {
        atomicAdd(&loss_sum[b], sl[0]);
        atomicAdd(&acnt[b], sc[0]);
    }
}

// ---------------- finalize ----------------
__global__ void k_final(const int* cnt_pos, const int* cnt_neg,
                        const float* loss_sum, const float* acnt, float* out) {
    float tot = 0.f, nv = 0.f;
    bool any = false;
    for (int b = 0; b < B_; ++b) {
        bool valid = (cnt_pos[b] >= 2) && (cnt_neg[b] > 0) && (acnt[b] > 0.f);
        float il = loss_sum[b] / fmaxf(acnt[b], 1.f);
        if (valid) { tot += il; nv += 1.f; any = true; }
    }
    out[0] = any ? tot / fmaxf(nv, 1.f) : 0.f;
}

extern "C" void kernel_launch(void* const* d_in, const int* in_sizes, int n_in,
                              void* d_out, int out_size, void* d_ws, size_t ws_size,
                              hipStream_t stream) {
    const float* features = (const float*)d_in[0];
    const int* labels = (const int*)d_in[1];
    float* out = (float*)d_out;

    // ---- workspace carve ----
    char* p = (char*)d_ws;
    float* pos_feat = (float*)p;                 p += (size_t)B_ * P_CAP * C_ * 4;
    float* neg_feat = (float*)p;                 p += (size_t)B_ * NEG_CAP * C_ * 4;
    float* partial = (float*)p;                  p += (size_t)B_ * SLICES * 2 * P_CAP * 4;
    int* pos_idx = (int*)p;                      p += (size_t)B_ * P_CAP * 4;
    int* neg_idx = (int*)p;                      p += (size_t)B_ * NEG_CAP * 4;
    int* cnt_pos = (int*)p;                      p += B_ * 4;
    int* cnt_neg = (int*)p;                      p += B_ * 4;
    float* loss_sum = (float*)p;                 p += B_ * 4;
    float* acnt = (float*)p;                     p += B_ * 4;
    unsigned char* fg = (unsigned char*)p;       p += (size_t)B_ * N_;
    unsigned char* t1 = (unsigned char*)p;       p += (size_t)B_ * N_;
    unsigned char* t2 = (unsigned char*)p;       p += (size_t)B_ * N_;

    const int threads = 256;
    const int vox_blocks = (B_ * N_ + threads - 1) / threads;

    k_init<<<1, 64, 0, stream>>>(cnt_pos, cnt_neg, loss_sum, acnt);
    k_fg<<<vox_blocks, threads, 0, stream>>>(labels, fg);
    k_dil<<<vox_blocks, threads, 0, stream>>>(fg, t1, 0, W_);   // along W
    k_dil<<<vox_blocks, threads, 0, stream>>>(t1, t2, 7, H_);   // along H
    k_compact<<<vox_blocks, threads, 0, stream>>>(t2, fg, pos_idx, neg_idx, cnt_pos, cnt_neg);
    const int gat_blocks = (B_ * (P_CAP + NEG_CAP) + threads - 1) / threads;
    k_gather<<<gat_blocks, threads, 0, stream>>>(features, pos_idx, neg_idx, cnt_pos, cnt_neg,
                                                 pos_feat, neg_feat);
    dim3 lgrid(SLICES, P_CAP / 256, B_);
    k_loss2<<<lgrid, 256, 0, stream>>>(pos_feat, neg_feat, cnt_pos, cnt_neg, partial);
    k_loss_fin<<<B_ * (P_CAP / 256), 256, 0, stream>>>(partial, cnt_pos, loss_sum, acnt);
    k_final<<<1, 1, 0, stream>>>(cnt_pos, cnt_neg, loss_sum, acnt, out);
}

// Round 3
// 398.833 us; speedup vs baseline: 2.4272x; 1.5820x over previous
//
#include <hip/hip_runtime.h>
#include <math.h>

#define B_ 2
#define C_ 32
#define D_ 64
#define H_ 128
#define W_ 128
#define N_ (D_*H_*W_)          // 1048576 = 2^20
#define NW_ (N_/64)            // 16384 words per image
#define P_CAP 2048
#define NEG_CAP 12288
#define PAD 5
#define EPS_ 1e-8f
#define SLICES 32
#define TA 4                   // anchors per thread

// ---------------- init: zero counters / accumulators ----------------
__global__ void k_init(int* cnt_pos, int* cnt_neg, float* loss_sum, float* acnt) {
    int t = threadIdx.x;
    if (t < B_) { cnt_pos[t] = 0; cnt_neg[t] = 0; loss_sum[t] = 0.f; acnt[t] = 0.f; }
}

// ---------------- pack fg bits + W-axis dilation (bitwise) ----------------
// word index = g>>6 ; within a 256-thread block, 4 words = 2 complete W-rows.
__global__ __launch_bounds__(256) void k_packW(const int* __restrict__ labels,
                                               unsigned long long* __restrict__ fgbits,
                                               unsigned long long* __restrict__ dilw) {
    const int g = blockIdx.x * 256 + threadIdx.x;
    const int lane = threadIdx.x & 63;
    const int w = threadIdx.x >> 6;            // wave id 0..3
    const int word = (blockIdx.x << 2) + w;    // global word index = g>>6

    unsigned long long fgw = __ballot(labels[g] > 0);
    __shared__ unsigned long long smem[4];
    if (lane == 0) { fgbits[word] = fgw; smem[w] = fgw; }
    __syncthreads();
    unsigned long long self = smem[w];
    unsigned long long other = smem[w ^ 1];
    unsigned long long out = self;
    if ((word & 1) == 0) {       // low word of the 128-bit row
#pragma unroll
        for (int k = 1; k <= PAD; ++k)
            out |= (self >> k) | (self << k) | (other << (64 - k));
    } else {                     // high word
#pragma unroll
        for (int k = 1; k <= PAD; ++k)
            out |= (self << k) | (self >> k) | (other >> (64 - k));
    }
    if (lane == 0) dilw[word] = out;
}

// ---------------- H-axis dilation on words ----------------
__global__ __launch_bounds__(256) void k_dilH(const unsigned long long* __restrict__ in,
                                              unsigned long long* __restrict__ out) {
    const int q = blockIdx.x * 256 + threadIdx.x;       // 0..B_*NW_-1
    const int qq = q & (NW_ - 1);
    const int h = (qq >> 1) & (H_ - 1);
    const int lo = (h >= PAD) ? -PAD : -h;
    const int hi = (h + PAD <= H_ - 1) ? PAD : (H_ - 1 - h);
    unsigned long long v = 0;
    for (int o = lo; o <= hi; ++o) v |= in[q + o * 2];
    out[q] = v;
}

// ---------------- D-axis dilation on words ----------------
__global__ __launch_bounds__(256) void k_dilD(const unsigned long long* __restrict__ in,
                                              unsigned long long* __restrict__ out) {
    const int q = blockIdx.x * 256 + threadIdx.x;
    const int qq = q & (NW_ - 1);
    const int d = qq >> 8;                               // d = qq / (H_*2)
    const int lo = (d >= PAD) ? -PAD : -d;
    const int hi = (d + PAD <= D_ - 1) ? PAD : (D_ - 1 - d);
    unsigned long long v = 0;
    for (int o = lo; o <= hi; ++o) v |= in[q + o * (H_ * 2)];
    out[q] = v;
}

// ---------------- fused compact + gather + normalize ----------------
// One wave per 64-voxel word; one atomic per nonzero mask per wave.
__global__ __launch_bounds__(256) void k_cg(const float* __restrict__ features,
                                            const unsigned long long* __restrict__ fgbits,
                                            const unsigned long long* __restrict__ dild,
                                            int* cnt_pos, int* cnt_neg,
                                            float* __restrict__ pos_feat,
                                            float* __restrict__ neg_feat) {
    const int g = blockIdx.x * 256 + threadIdx.x;
    const int lane = threadIdx.x & 63;
    const int word = g >> 6;
    const int b = g >> 20;
    const int n = g & (N_ - 1);

    unsigned long long fgw = fgbits[word];               // wave-uniform load
    unsigned long long rimw = dild[word] & ~fgw;
    if ((fgw | rimw) == 0) return;

    int basep = 0, basen = 0;
    if (lane == 0) {
        if (fgw)  basep = atomicAdd(&cnt_pos[b], __popcll(fgw));
        if (rimw) basen = atomicAdd(&cnt_neg[b], __popcll(rimw));
    }
    basep = __shfl(basep, 0);
    basen = __shfl(basen, 0);

    const unsigned long long ltmask = (lane == 0) ? 0ull : (~0ull >> (64 - lane));
    const bool is_fg = (fgw >> lane) & 1;
    const bool is_rim = (rimw >> lane) & 1;
    if (!is_fg && !is_rim) return;

    int slot; float* dst;
    if (is_fg) {
        slot = basep + __popcll(fgw & ltmask);
        if (slot >= P_CAP) return;
        dst = pos_feat + ((size_t)b * P_CAP + slot) * C_;
    } else {
        slot = basen + __popcll(rimw & ltmask);
        if (slot >= NEG_CAP) return;
        dst = neg_feat + ((size_t)b * NEG_CAP + slot) * C_;
    }

    const float* fbase = features + (size_t)b * C_ * N_ + n;
    float v[C_];
    float ss = 0.f;
#pragma unroll
    for (int c = 0; c < C_; ++c) {
        float x = fbase[(size_t)c * N_];
        v[c] = x;
        ss += x * x;
    }
    float inv = 1.0f / fmaxf(sqrtf(ss), 1e-12f);
#pragma unroll
    for (int c = 0; c < C_; ++c) dst[c] = v[c] * inv;
}

// ---------------- partner-sliced loss, fixed softmax shift m=10 ----------------
// partial layout: [B][SLICES][2][P_CAP]
__global__ __launch_bounds__(256) void k_loss2(const float* __restrict__ pos_feat,
                                               const float* __restrict__ neg_feat,
                                               const int* __restrict__ cnt_pos,
                                               const int* __restrict__ cnt_neg,
                                               float* __restrict__ partial) {
    const int slice = blockIdx.x;
    const int tile  = blockIdx.y;
    const int b     = blockIdx.z;
    const int np = min(cnt_pos[b], P_CAP);
    const int nn = min(cnt_neg[b], NEG_CAP);
    const int abase = tile * 256;
    if (abase >= np) return;
    const int total = np + nn;
    const int tid = threadIdx.x;
    const int lane = tid & 63;
    const int w = __builtin_amdgcn_readfirstlane(tid >> 6);

    const int a0 = abase + lane * TA;
    float A[TA][C_];
#pragma unroll
    for (int i = 0; i < TA; ++i) {
        const float4* p = (const float4*)(pos_feat + ((size_t)b * P_CAP + (a0 + i)) * C_);
#pragma unroll
        for (int q = 0; q < 8; ++q) {
            float4 v = p[q];
            A[i][4*q+0] = v.x; A[i][4*q+1] = v.y; A[i][4*q+2] = v.z; A[i][4*q+3] = v.w;
        }
    }

    float ps[TA] = {0.f, 0.f, 0.f, 0.f};
    float ns[TA] = {0.f, 0.f, 0.f, 0.f};

    const int per = (total + SLICES - 1) / SLICES;
    const int r0 = slice * per;
    const int r1 = min(r0 + per, total);

#pragma unroll 2
    for (int gr = r0 + w; gr < r1; gr += 4) {
        const float4* row4 = (gr < np)
            ? (const float4*)(pos_feat + ((size_t)b * P_CAP + gr) * C_)
            : (const float4*)(neg_feat + ((size_t)b * NEG_CAP + (gr - np)) * C_);
        float d0 = 0.f, d1 = 0.f, d2 = 0.f, d3 = 0.f;
#pragma unroll
        for (int q = 0; q < 8; ++q) {
            float4 v = row4[q];
            d0 = fmaf(v.x, A[0][4*q+0], d0); d0 = fmaf(v.y, A[0][4*q+1], d0);
            d0 = fmaf(v.z, A[0][4*q+2], d0); d0 = fmaf(v.w, A[0][4*q+3], d0);
            d1 = fmaf(v.x, A[1][4*q+0], d1); d1 = fmaf(v.y, A[1][4*q+1], d1);
            d1 = fmaf(v.z, A[1][4*q+2], d1); d1 = fmaf(v.w, A[1][4*q+3], d1);
            d2 = fmaf(v.x, A[2][4*q+0], d2); d2 = fmaf(v.y, A[2][4*q+1], d2);
            d2 = fmaf(v.z, A[2][4*q+2], d2); d2 = fmaf(v.w, A[2][4*q+3], d2);
            d3 = fmaf(v.x, A[3][4*q+0], d3); d3 = fmaf(v.y, A[3][4*q+1], d3);
            d3 = fmaf(v.z, A[3][4*q+2], d3); d3 = fmaf(v.w, A[3][4*q+3], d3);
        }
        float e0 = __expf(fmaf(d0, 10.f, -10.f));
        float e1 = __expf(fmaf(d1, 10.f, -10.f));
        float e2 = __expf(fmaf(d2, 10.f, -10.f));
        float e3 = __expf(fmaf(d3, 10.f, -10.f));
        if (gr < np) {
            ps[0] += (gr == a0 + 0) ? 0.f : e0;
            ps[1] += (gr == a0 + 1) ? 0.f : e1;
            ps[2] += (gr == a0 + 2) ? 0.f : e2;
            ps[3] += (gr == a0 + 3) ? 0.f : e3;
        } else {
            ns[0] += e0; ns[1] += e1; ns[2] += e2; ns[3] += e3;
        }
    }

    __shared__ float redP[4][256];
    __shared__ float redN[4][256];
    const int slot = lane * TA;
#pragma unroll
    for (int i = 0; i < TA; ++i) { redP[w][slot + i] = ps[i]; redN[w][slot + i] = ns[i]; }
    __syncthreads();
    {
        float p = redP[0][tid] + redP[1][tid] + redP[2][tid] + redP[3][tid];
        float n = redN[0][tid] + redN[1][tid] + redN[2][tid] + redN[3][tid];
        float* dst = partial + ((size_t)(b * SLICES + slice) * 2) * P_CAP;
        dst[abase + tid] = p;
        dst[P_CAP + abase + tid] = n;
    }
}

// ---------------- per-anchor finalize ----------------
__global__ __launch_bounds__(256) void k_loss_fin(const float* __restrict__ partial,
                                                  const int* __restrict__ cnt_pos,
                                                  float* __restrict__ loss_sum,
                                                  float* __restrict__ acnt) {
    const int blocks_per_b = P_CAP / 256;
    const int b = blockIdx.x / blocks_per_b;
    const int a = (blockIdx.x % blocks_per_b) * 256 + threadIdx.x;
    const int np = min(cnt_pos[b], P_CAP);
    const int tid = threadIdx.x;
    float loss = 0.f, cnt = 0.f;
    if (a < np) {
        float num = 0.f, den = 0.f;
        for (int s = 0; s < SLICES; ++s) {
            const float* base = partial + ((size_t)(b * SLICES + s) * 2) * P_CAP;
            num += base[a];
            den += base[P_CAP + a];
        }
        if (num > 0.f) {
            den += num;
            num += EPS_; den += EPS_;
            loss = __logf(den) - __logf(num);
            cnt = 1.f;
        }
    }
    __shared__ float sl[256], sc[256];
    sl[tid] = loss; sc[tid] = cnt;
    __syncthreads();
    for (int off = 128; off > 0; off >>= 1) {
        if (tid < off) { sl[tid] += sl[tid + off]; sc[tid] += sc[tid + off]; }
        __syncthreads();
    }
    if (tid == 0 && sc[0] > 0.f) {
        atomicAdd(&loss_sum[b], sl[0]);
        atomicAdd(&acnt[b], sc[0]);
    }
}

// ---------------- finalize ----------------
__global__ void k_final(const int* cnt_pos, const int* cnt_neg,
                        const float* loss_sum, const float* acnt, float* out) {
    float tot = 0.f, nv = 0.f;
    bool any = false;
    for (int b = 0; b < B_; ++b) {
        bool valid = (cnt_pos[b] >= 2) && (cnt_neg[b] > 0) && (acnt[b] > 0.f);
        float il = loss_sum[b] / fmaxf(acnt[b], 1.f);
        if (valid) { tot += il; nv += 1.f; any = true; }
    }
    out[0] = any ? tot / fmaxf(nv, 1.f) : 0.f;
}

extern "C" void kernel_launch(void* const* d_in, const int* in_sizes, int n_in,
                              void* d_out, int out_size, void* d_ws, size_t ws_size,
                              hipStream_t stream) {
    const float* features = (const float*)d_in[0];
    const int* labels = (const int*)d_in[1];
    float* out = (float*)d_out;

    // ---- workspace carve ----
    char* p = (char*)d_ws;
    float* pos_feat = (float*)p;                 p += (size_t)B_ * P_CAP * C_ * 4;
    float* neg_feat = (float*)p;                 p += (size_t)B_ * NEG_CAP * C_ * 4;
    float* partial = (float*)p;                  p += (size_t)B_ * SLICES * 2 * P_CAP * 4;
    unsigned long long* fgbits = (unsigned long long*)p;  p += (size_t)B_ * NW_ * 8;
    unsigned long long* dilw = (unsigned long long*)p;    p += (size_t)B_ * NW_ * 8;
    unsigned long long* dilh = (unsigned long long*)p;    p += (size_t)B_ * NW_ * 8;
    unsigned long long* dild = (unsigned long long*)p;    p += (size_t)B_ * NW_ * 8;
    int* cnt_pos = (int*)p;                      p += B_ * 4;
    int* cnt_neg = (int*)p;                      p += B_ * 4;
    float* loss_sum = (float*)p;                 p += B_ * 4;
    float* acnt = (float*)p;                     p += B_ * 4;

    const int threads = 256;
    const int vox_blocks = B_ * N_ / threads;          // 8192
    const int word_blocks = B_ * NW_ / threads;        // 128

    k_init<<<1, 64, 0, stream>>>(cnt_pos, cnt_neg, loss_sum, acnt);
    k_packW<<<vox_blocks, threads, 0, stream>>>(labels, fgbits, dilw);
    k_dilH<<<word_blocks, threads, 0, stream>>>(dilw, dilh);
    k_dilD<<<word_blocks, threads, 0, stream>>>(dilh, dild);
    k_cg<<<vox_blocks, threads, 0, stream>>>(features, fgbits, dild,
                                             cnt_pos, cnt_neg, pos_feat, neg_feat);
    dim3 lgrid(SLICES, P_CAP / 256, B_);
    k_loss2<<<lgrid, 256, 0, stream>>>(pos_feat, neg_feat, cnt_pos, cnt_neg, partial);
    k_loss_fin<<<B_ * (P_CAP / 256), 256, 0, stream>>>(partial, cnt_pos, loss_sum, acnt);
    k_final<<<1, 1, 0, stream>>>(cnt_pos, cnt_neg, loss_sum, acnt, out);
}

// Round 4
// 380.177 us; speedup vs baseline: 2.5463x; 1.0491x over previous
//
#include <hip/hip_runtime.h>
#include <math.h>

#define B_ 2
#define C_ 32
#define D_ 64
#define H_ 128
#define W_ 128
#define N_ (D_*H_*W_)          // 1048576 = 2^20
#define NW_ (N_/64)            // 16384 words per image
#define P_CAP 2048
#define NEG_CAP 12288
#define PAD 5
#define EPS_ 1e-8f
#define SLICES 64
#define TA 4                   // anchors per thread

// ---------------- init: zero counters / accumulators ----------------
__global__ void k_init(int* cnt_pos, int* cnt_neg, float* loss_sum, float* acnt) {
    int t = threadIdx.x;
    if (t < B_) { cnt_pos[t] = 0; cnt_neg[t] = 0; loss_sum[t] = 0.f; acnt[t] = 0.f; }
}

// ---------------- pack fg bits + W-axis dilation (bitwise) ----------------
__global__ __launch_bounds__(256) void k_packW(const int* __restrict__ labels,
                                               unsigned long long* __restrict__ fgbits,
                                               unsigned long long* __restrict__ dilw) {
    const int g = blockIdx.x * 256 + threadIdx.x;
    const int lane = threadIdx.x & 63;
    const int w = threadIdx.x >> 6;            // wave id 0..3
    const int word = (blockIdx.x << 2) + w;    // global word index = g>>6

    unsigned long long fgw = __ballot(labels[g] > 0);
    __shared__ unsigned long long smem[4];
    if (lane == 0) { fgbits[word] = fgw; smem[w] = fgw; }
    __syncthreads();
    unsigned long long self = smem[w];
    unsigned long long other = smem[w ^ 1];
    unsigned long long out = self;
    if ((word & 1) == 0) {       // low word of the 128-bit row
#pragma unroll
        for (int k = 1; k <= PAD; ++k)
            out |= (self >> k) | (self << k) | (other << (64 - k));
    } else {                     // high word
#pragma unroll
        for (int k = 1; k <= PAD; ++k)
            out |= (self << k) | (self >> k) | (other >> (64 - k));
    }
    if (lane == 0) dilw[word] = out;
}

// ---------------- H-axis dilation on words ----------------
__global__ __launch_bounds__(256) void k_dilH(const unsigned long long* __restrict__ in,
                                              unsigned long long* __restrict__ out) {
    const int q = blockIdx.x * 256 + threadIdx.x;       // 0..B_*NW_-1
    const int qq = q & (NW_ - 1);
    const int h = (qq >> 1) & (H_ - 1);
    const int lo = (h >= PAD) ? -PAD : -h;
    const int hi = (h + PAD <= H_ - 1) ? PAD : (H_ - 1 - h);
    unsigned long long v = 0;
    for (int o = lo; o <= hi; ++o) v |= in[q + o * 2];
    out[q] = v;
}

// ---------------- D-axis dilation on words ----------------
__global__ __launch_bounds__(256) void k_dilD(const unsigned long long* __restrict__ in,
                                              unsigned long long* __restrict__ out) {
    const int q = blockIdx.x * 256 + threadIdx.x;
    const int qq = q & (NW_ - 1);
    const int d = qq >> 8;                               // d = qq / (H_*2)
    const int lo = (d >= PAD) ? -PAD : -d;
    const int hi = (d + PAD <= D_ - 1) ? PAD : (D_ - 1 - d);
    unsigned long long v = 0;
    for (int o = lo; o <= hi; ++o) v |= in[q + o * (H_ * 2)];
    out[q] = v;
}

// ---------------- fused compact + gather + normalize ----------------
__global__ __launch_bounds__(256) void k_cg(const float* __restrict__ features,
                                            const unsigned long long* __restrict__ fgbits,
                                            const unsigned long long* __restrict__ dild,
                                            int* cnt_pos, int* cnt_neg,
                                            float* __restrict__ pos_feat,
                                            float* __restrict__ neg_feat) {
    const int g = blockIdx.x * 256 + threadIdx.x;
    const int lane = threadIdx.x & 63;
    const int word = g >> 6;
    const int b = g >> 20;
    const int n = g & (N_ - 1);

    unsigned long long fgw = fgbits[word];               // wave-uniform load
    unsigned long long rimw = dild[word] & ~fgw;
    if ((fgw | rimw) == 0) return;

    int basep = 0, basen = 0;
    if (lane == 0) {
        if (fgw)  basep = atomicAdd(&cnt_pos[b], __popcll(fgw));
        if (rimw) basen = atomicAdd(&cnt_neg[b], __popcll(rimw));
    }
    basep = __shfl(basep, 0);
    basen = __shfl(basen, 0);

    const unsigned long long ltmask = (lane == 0) ? 0ull : (~0ull >> (64 - lane));
    const bool is_fg = (fgw >> lane) & 1;
    const bool is_rim = (rimw >> lane) & 1;
    if (!is_fg && !is_rim) return;

    int slot; float* dst;
    if (is_fg) {
        slot = basep + __popcll(fgw & ltmask);
        if (slot >= P_CAP) return;
        dst = pos_feat + ((size_t)b * P_CAP + slot) * C_;
    } else {
        slot = basen + __popcll(rimw & ltmask);
        if (slot >= NEG_CAP) return;
        dst = neg_feat + ((size_t)b * NEG_CAP + slot) * C_;
    }

    const float* fbase = features + (size_t)b * C_ * N_ + n;
    float v[C_];
    float ss = 0.f;
#pragma unroll
    for (int c = 0; c < C_; ++c) {
        float x = fbase[(size_t)c * N_];
        v[c] = x;
        ss += x * x;
    }
    float inv = 1.0f / fmaxf(sqrtf(ss), 1e-12f);
#pragma unroll
    for (int c = 0; c < C_; ++c) dst[c] = v[c] * inv;
}

// ---------------- partner-sliced loss, fixed softmax shift m=10 ----------------
// partial layout: [B][SLICES][2][P_CAP]
__device__ __forceinline__ void dot4x(const float4* __restrict__ row4,
                                      const float A[TA][C_], float d[TA]) {
    d[0] = d[1] = d[2] = d[3] = 0.f;
#pragma unroll
    for (int q = 0; q < 8; ++q) {
        float4 v = row4[q];
#pragma unroll
        for (int i = 0; i < TA; ++i) {
            d[i] = fmaf(v.x, A[i][4*q+0], d[i]);
            d[i] = fmaf(v.y, A[i][4*q+1], d[i]);
            d[i] = fmaf(v.z, A[i][4*q+2], d[i]);
            d[i] = fmaf(v.w, A[i][4*q+3], d[i]);
        }
    }
}

__global__ __launch_bounds__(256, 3) void k_loss2(const float* __restrict__ pos_feat,
                                                  const float* __restrict__ neg_feat,
                                                  const int* __restrict__ cnt_pos,
                                                  const int* __restrict__ cnt_neg,
                                                  float* __restrict__ partial) {
    const int slice = blockIdx.x;
    const int tile  = blockIdx.y;
    const int b     = blockIdx.z;
    const int np = min(cnt_pos[b], P_CAP);
    const int nn = min(cnt_neg[b], NEG_CAP);
    const int abase = tile * 256;
    if (abase >= np) return;
    const int total = np + nn;
    const int tid = threadIdx.x;
    const int lane = tid & 63;
    const int w = __builtin_amdgcn_readfirstlane(tid >> 6);

    const int a0 = abase + lane * TA;
    float A[TA][C_];
#pragma unroll
    for (int i = 0; i < TA; ++i) {
        const float4* p = (const float4*)(pos_feat + ((size_t)b * P_CAP + (a0 + i)) * C_);
#pragma unroll
        for (int q = 0; q < 8; ++q) {
            float4 v = p[q];
            A[i][4*q+0] = v.x; A[i][4*q+1] = v.y; A[i][4*q+2] = v.z; A[i][4*q+3] = v.w;
        }
    }

    float ps[TA] = {0.f, 0.f, 0.f, 0.f};
    float ns[TA] = {0.f, 0.f, 0.f, 0.f};

    const int per = (total + SLICES - 1) / SLICES;
    const int r0 = slice * per;
    const int r1 = min(r0 + per, total);

    // ---- positive partners in [r0, min(r1,np)) ----
    const int pEnd = min(r1, np);
    const float4* pbase4 = (const float4*)(pos_feat + (size_t)b * P_CAP * C_);
    for (int gr = r0 + w; gr < pEnd; gr += 4) {
        float d[TA];
        dot4x(pbase4 + gr * 8, A, d);
#pragma unroll
        for (int i = 0; i < TA; ++i) {
            float e = __expf(fmaf(d[i], 10.f, -10.f));
            ps[i] += (gr == a0 + i) ? 0.f : e;
        }
    }
    // ---- negative partners in [max(r0,np), r1) ----
    const int s0 = max(r0, np);
    const float4* nbase4 = (const float4*)(neg_feat + (size_t)b * NEG_CAP * C_);
    for (int gr = s0 + w; gr < r1; gr += 4) {
        float d[TA];
        dot4x(nbase4 + (gr - np) * 8, A, d);
#pragma unroll
        for (int i = 0; i < TA; ++i)
            ns[i] += __expf(fmaf(d[i], 10.f, -10.f));
    }

    __shared__ float redP[4][256];
    __shared__ float redN[4][256];
    const int slot = lane * TA;
#pragma unroll
    for (int i = 0; i < TA; ++i) { redP[w][slot + i] = ps[i]; redN[w][slot + i] = ns[i]; }
    __syncthreads();
    {
        float p = redP[0][tid] + redP[1][tid] + redP[2][tid] + redP[3][tid];
        float n = redN[0][tid] + redN[1][tid] + redN[2][tid] + redN[3][tid];
        float* dst = partial + ((size_t)(b * SLICES + slice) * 2) * P_CAP;
        dst[abase + tid] = p;
        dst[P_CAP + abase + tid] = n;
    }
}

// ---------------- per-anchor finalize ----------------
__global__ __launch_bounds__(256) void k_loss_fin(const float* __restrict__ partial,
                                                  const int* __restrict__ cnt_pos,
                                                  float* __restrict__ loss_sum,
                                                  float* __restrict__ acnt) {
    const int blocks_per_b = P_CAP / 256;
    const int b = blockIdx.x / blocks_per_b;
    const int a = (blockIdx.x % blocks_per_b) * 256 + threadIdx.x;
    const int np = min(cnt_pos[b], P_CAP);
    const int tid = threadIdx.x;
    float loss = 0.f, cnt = 0.f;
    if (a < np) {
        float num = 0.f, den = 0.f;
        for (int s = 0; s < SLICES; ++s) {
            const float* base = partial + ((size_t)(b * SLICES + s) * 2) * P_CAP;
            num += base[a];
            den += base[P_CAP + a];
        }
        if (num > 0.f) {
            den += num;
            num += EPS_; den += EPS_;
            loss = __logf(den) - __logf(num);
            cnt = 1.f;
        }
    }
    __shared__ float sl[256], sc[256];
    sl[tid] = loss; sc[tid] = cnt;
    __syncthreads();
    for (int off = 128; off > 0; off >>= 1) {
        if (tid < off) { sl[tid] += sl[tid + off]; sc[tid] += sc[tid + off]; }
        __syncthreads();
    }
    if (tid == 0 && sc[0] > 0.f) {
        atomicAdd(&loss_sum[b], sl[0]);
        atomicAdd(&acnt[b], sc[0]);
    }
}

// ---------------- finalize ----------------
__global__ void k_final(const int* cnt_pos, const int* cnt_neg,
                        const float* loss_sum, const float* acnt, float* out) {
    float tot = 0.f, nv = 0.f;
    bool any = false;
    for (int b = 0; b < B_; ++b) {
        bool valid = (cnt_pos[b] >= 2) && (cnt_neg[b] > 0) && (acnt[b] > 0.f);
        float il = loss_sum[b] / fmaxf(acnt[b], 1.f);
        if (valid) { tot += il; nv += 1.f; any = true; }
    }
    out[0] = any ? tot / fmaxf(nv, 1.f) : 0.f;
}

extern "C" void kernel_launch(void* const* d_in, const int* in_sizes, int n_in,
                              void* d_out, int out_size, void* d_ws, size_t ws_size,
                              hipStream_t stream) {
    const float* features = (const float*)d_in[0];
    const int* labels = (const int*)d_in[1];
    float* out = (float*)d_out;

    // ---- workspace carve ----
    char* p = (char*)d_ws;
    float* pos_feat = (float*)p;                 p += (size_t)B_ * P_CAP * C_ * 4;
    float* neg_feat = (float*)p;                 p += (size_t)B_ * NEG_CAP * C_ * 4;
    float* partial = (float*)p;                  p += (size_t)B_ * SLICES * 2 * P_CAP * 4;
    unsigned long long* fgbits = (unsigned long long*)p;  p += (size_t)B_ * NW_ * 8;
    unsigned long long* dilw = (unsigned long long*)p;    p += (size_t)B_ * NW_ * 8;
    unsigned long long* dilh = (unsigned long long*)p;    p += (size_t)B_ * NW_ * 8;
    unsigned long long* dild = (unsigned long long*)p;    p += (size_t)B_ * NW_ * 8;
    int* cnt_pos = (int*)p;                      p += B_ * 4;
    int* cnt_neg = (int*)p;                      p += B_ * 4;
    float* loss_sum = (float*)p;                 p += B_ * 4;
    float* acnt = (float*)p;                     p += B_ * 4;

    const int threads = 256;
    const int vox_blocks = B_ * N_ / threads;          // 8192
    const int word_blocks = B_ * NW_ / threads;        // 128

    k_init<<<1, 64, 0, stream>>>(cnt_pos, cnt_neg, loss_sum, acnt);
    k_packW<<<vox_blocks, threads, 0, stream>>>(labels, fgbits, dilw);
    k_dilH<<<word_blocks, threads, 0, stream>>>(dilw, dilh);
    k_dilD<<<word_blocks, threads, 0, stream>>>(dilh, dild);
    k_cg<<<vox_blocks, threads, 0, stream>>>(features, fgbits, dild,
                                             cnt_pos, cnt_neg, pos_feat, neg_feat);
    dim3 lgrid(SLICES, P_CAP / 256, B_);
    k_loss2<<<lgrid, 256, 0, stream>>>(pos_feat, neg_feat, cnt_pos, cnt_neg, partial);
    k_loss_fin<<<B_ * (P_CAP / 256), 256, 0, stream>>>(partial, cnt_pos, loss_sum, acnt);
    k_final<<<1, 1, 0, stream>>>(cnt_pos, cnt_neg, loss_sum, acnt, out);
}